// Round 7
// baseline (421.035 us; speedup 1.0000x reference)
//
#include <hip/hip_runtime.h>
#include <stdint.h>

#define DD 128
#define LDSROW 136  // 128 cols + 8 pad (ushort) -> 272B row stride

typedef __attribute__((ext_vector_type(8))) short short8;
typedef __attribute__((ext_vector_type(4))) float float4v;

// ---------- bf16 helpers (RTNE) ----------
__device__ __forceinline__ unsigned short f2bf(float f) {
  unsigned u = __float_as_uint(f);
  unsigned r = u + 0x7fffu + ((u >> 16) & 1u);
  return (unsigned short)(r >> 16);
}
__device__ __forceinline__ unsigned pack2(float a, float b) {
  return (unsigned)f2bf(a) | ((unsigned)f2bf(b) << 16);
}
__device__ __forceinline__ float2 unpack2(unsigned p) {
  float2 r;
  r.x = __uint_as_float(p << 16);
  r.y = __uint_as_float(p & 0xffff0000u);
  return r;
}

// ---------- CSR build: deg atomics + weight prep fused (independent work, one dispatch) ----------
__global__ __launch_bounds__(256) void k_deg_prep(const int* __restrict__ dst, int* deg, int e, int eb,
                                                  const float* __restrict__ W1, const float* __restrict__ W2,
                                                  const float* __restrict__ Wself, const float* __restrict__ Wneigh,
                                                  unsigned* __restrict__ wfrag) {
  int b = blockIdx.x;
  if (b < eb) {
    int i = b * 256 + threadIdx.x;
    if (i < e) atomicAdd(&deg[dst[i]], 1);
  } else {
    int gid = (b - eb) * 256 + threadIdx.x;  // 0 .. 65535
    int m = gid >> 13;
    int r = gid & 8191;
    int p = r & 3;
    int lane = (r >> 2) & 63;
    int t = (r >> 8) & 3;
    int c = r >> 10;
    const float* W;
    if (m == 0) W = W1;
    else if (m == 1) W = W2;
    else if (m < 5) W = Wself + (size_t)(m - 2) * DD * DD;
    else W = Wneigh + (size_t)(m - 5) * DD * DD;
    int n = c * 16 + (lane & 15);
    int k = t * 32 + (lane >> 4) * 8 + 2 * p;
    wfrag[gid] = pack2(W[(size_t)k * DD + n], W[(size_t)(k + 1) * DD + n]);
  }
}

__global__ __launch_bounds__(1024) void k_scan1(const int* __restrict__ deg, int* __restrict__ incl,
                                                int* __restrict__ bsum, int n) {
  __shared__ int sh[1024];
  int t = threadIdx.x;
  int i = blockIdx.x * 1024 + t;
  int v = (i < n) ? deg[i] : 0;
  sh[t] = v;
  __syncthreads();
#pragma unroll
  for (int off = 1; off < 1024; off <<= 1) {
    int add = (t >= off) ? sh[t - off] : 0;
    __syncthreads();
    sh[t] += add;
    __syncthreads();
  }
  if (i < n) incl[i] = sh[t];
  if (t == 1023) bsum[blockIdx.x] = sh[1023];
}

__global__ __launch_bounds__(1024) void k_scan3(const int* __restrict__ deg, const int* __restrict__ incl,
                                                const int* __restrict__ bsum, int* __restrict__ rowstart,
                                                int* __restrict__ cursor, int n, int nb) {
  __shared__ int sboff;
  int t = threadIdx.x;
  if (t < 64) {
    int orig = (t < nb) ? bsum[t] : 0;
    int v = orig;
#pragma unroll
    for (int off = 1; off < 64; off <<= 1) {
      int u = __shfl_up(v, off);
      if (t >= off) v += u;
    }
    if (t == (int)blockIdx.x) sboff = v - orig;
  }
  __syncthreads();
  int i = blockIdx.x * 1024 + t;
  if (i >= n) return;
  int d = deg[i];
  int excl = sboff + incl[i] - d;
  rowstart[i] = excl;
  cursor[i] = excl;
  if (i == n - 1) rowstart[n] = excl + d;
}

// ---------- range-partitioned fill (L2-local write windows) ----------
__global__ __launch_bounds__(256) void k_fill_r(const int* __restrict__ src, const int* __restrict__ dst,
                                                int* cursor, int* __restrict__ esrc, int e, int rstep) {
  int range = blockIdx.x & 7;
  int i = (blockIdx.x >> 3) * 256 + threadIdx.x;
  if (i >= e) return;
  int d = dst[i];
  int lo = range * rstep;
  if (d >= lo && d < lo + rstep) {
    int p = atomicAdd(&cursor[d], 1);
    esrc[p] = src[i];
  }
}

// ---------- fused fc_in: out = tanh(h@W1+b1)@W2+b2  (bf16 out), 64 rows/block ----------
__global__ __launch_bounds__(256) void k_fc12(const float* __restrict__ h,
                                              const uint4* __restrict__ wf1, const uint4* __restrict__ wf2,
                                              const float* __restrict__ b1, const float* __restrict__ b2,
                                              unsigned short* __restrict__ outbf, int n) {
  __shared__ unsigned short sT[64 * LDSROW];
  int tid = threadIdx.x, w = tid >> 6, lane = tid & 63;
  int q = lane >> 4, nn = lane & 15;
  int r0 = (blockIdx.x * 4 + w) * 16;
  int rr = r0 + nn; if (rr >= n) rr = n - 1;
  short8 a[4];
  {
    const float* X = h + (size_t)rr * DD;
#pragma unroll
    for (int t = 0; t < 4; ++t) {
      int k0 = t * 32 + q * 8;
      float4 f0 = *(const float4*)&X[k0];
      float4 f1 = *(const float4*)&X[k0 + 4];
      uint4 u;
      u.x = pack2(f0.x, f0.y); u.y = pack2(f0.z, f0.w);
      u.z = pack2(f1.x, f1.y); u.w = pack2(f1.z, f1.w);
      a[t] = __builtin_bit_cast(short8, u);
    }
  }
  float4v acc[8];
#pragma unroll
  for (int c = 0; c < 8; ++c) acc[c] = (float4v){0.f, 0.f, 0.f, 0.f};
#pragma unroll
  for (int c = 0; c < 8; ++c) {
#pragma unroll
    for (int t = 0; t < 4; ++t) {
      short8 b = __builtin_bit_cast(short8, wf1[(c * 4 + t) * 64 + lane]);
      acc[c] = __builtin_amdgcn_mfma_f32_16x16x32_bf16(a[t], b, acc[c], 0, 0, 0);
    }
  }
#pragma unroll
  for (int c = 0; c < 8; ++c) {
    float bc = b1[c * 16 + nn];
#pragma unroll
    for (int g = 0; g < 4; ++g) {
      int lr = w * 16 + q * 4 + g;
      sT[lr * LDSROW + c * 16 + nn] = f2bf(tanhf(acc[c][g] + bc));
    }
  }
  __syncthreads();
  short8 a2[4];
#pragma unroll
  for (int t = 0; t < 4; ++t) {
    const uint4* p = (const uint4*)&sT[(w * 16 + nn) * LDSROW + (t * 4 + q) * 8];
    a2[t] = __builtin_bit_cast(short8, *p);
  }
  float4v acc2[8];
#pragma unroll
  for (int c = 0; c < 8; ++c) acc2[c] = (float4v){0.f, 0.f, 0.f, 0.f};
#pragma unroll
  for (int c = 0; c < 8; ++c) {
#pragma unroll
    for (int t = 0; t < 4; ++t) {
      short8 b = __builtin_bit_cast(short8, wf2[(c * 4 + t) * 64 + lane]);
      acc2[c] = __builtin_amdgcn_mfma_f32_16x16x32_bf16(a2[t], b, acc2[c], 0, 0, 0);
    }
  }
#pragma unroll
  for (int c = 0; c < 8; ++c) {
    float bc = b2[c * 16 + nn];
#pragma unroll
    for (int g = 0; g < 4; ++g) {
      int row = r0 + q * 4 + g;
      if (row < n) outbf[(size_t)row * DD + c * 16 + nn] = f2bf(acc2[c][g] + bc);
    }
  }
}

// ---------- fused SAGE layer v2: each 16-lane group aggregates 4 rows CONCURRENTLY ----------
// 16 lanes own a full 256B bf16 row (lane nn holds cols 8nn..8nn+7) -> no cross-lane reduce;
// 4 independent gather chains per group (16/wave) sustained across all edge iterations.
// ACT: 1 tanh, 2 silu
template <int ACT, bool OUTF32>
__global__ __launch_bounds__(256) void k_layer(const uint4* __restrict__ X,
                                               const int* __restrict__ rowstart, const int* __restrict__ esrc,
                                               const uint4* __restrict__ wfs, const uint4* __restrict__ wfn,
                                               const float* __restrict__ bias, void* __restrict__ outp, int n) {
  __shared__ unsigned short sT[64 * LDSROW];
  int tid = threadIdx.x, w = tid >> 6, lane = tid & 63;
  int q = lane >> 4, nn = lane & 15;
  int blk0 = blockIdx.x * 64;
  // ---- gather phase ----
  int lr0 = w * 16 + q * 4;  // this group's first local row
  int beg[4], cnt[4];
  int maxc = 0;
#pragma unroll
  for (int i = 0; i < 4; ++i) {
    int r = blk0 + lr0 + i;
    int rc = (r < n) ? r : (n - 1);
    int b = rowstart[rc];
    int c = (r < n) ? (rowstart[rc + 1] - b) : 0;
    beg[i] = b; cnt[i] = c;
    maxc = (c > maxc) ? c : maxc;
  }
  float acc[4][8];
#pragma unroll
  for (int i = 0; i < 4; ++i)
#pragma unroll
    for (int k = 0; k < 8; ++k) acc[i][k] = 0.f;
#pragma unroll 2
  for (int it = 0; it < maxc; ++it) {
#pragma unroll
    for (int i = 0; i < 4; ++i) {
      if (it < cnt[i]) {
        int s = esrc[beg[i] + it];
        uint4 v = X[(size_t)s * 16 + nn];
        const unsigned* u = (const unsigned*)&v;
#pragma unroll
        for (int k = 0; k < 4; ++k) {
          float2 f = unpack2(u[k]);
          acc[i][2 * k] += f.x;
          acc[i][2 * k + 1] += f.y;
        }
      }
    }
  }
#pragma unroll
  for (int i = 0; i < 4; ++i) {
    if (blk0 + lr0 + i < n) {
      float inv = 1.0f / (float)(cnt[i] > 1 ? cnt[i] : 1);
      uint4 o;
      o.x = pack2(acc[i][0] * inv, acc[i][1] * inv);
      o.y = pack2(acc[i][2] * inv, acc[i][3] * inv);
      o.z = pack2(acc[i][4] * inv, acc[i][5] * inv);
      o.w = pack2(acc[i][6] * inv, acc[i][7] * inv);
      *(uint4*)&sT[(lr0 + i) * LDSROW + nn * 8] = o;
    }
  }
  __syncthreads();
  // ---- GEMM phase ----
  int r0 = blk0 + w * 16;
  int rr = r0 + nn; if (rr >= n) rr = n - 1;
  short8 a[4], g[4];
  {
    const uint4* Xr = X + (size_t)rr * 16;
#pragma unroll
    for (int t = 0; t < 4; ++t) {
      a[t] = __builtin_bit_cast(short8, Xr[t * 4 + q]);
      const uint4* p = (const uint4*)&sT[(w * 16 + nn) * LDSROW + (t * 4 + q) * 8];
      g[t] = __builtin_bit_cast(short8, *p);
    }
  }
  float4v acc2[8];
#pragma unroll
  for (int c = 0; c < 8; ++c) acc2[c] = (float4v){0.f, 0.f, 0.f, 0.f};
#pragma unroll
  for (int c = 0; c < 8; ++c) {
#pragma unroll
    for (int t = 0; t < 4; ++t) {
      short8 b = __builtin_bit_cast(short8, wfs[(c * 4 + t) * 64 + lane]);
      acc2[c] = __builtin_amdgcn_mfma_f32_16x16x32_bf16(a[t], b, acc2[c], 0, 0, 0);
    }
#pragma unroll
    for (int t = 0; t < 4; ++t) {
      short8 b = __builtin_bit_cast(short8, wfn[(c * 4 + t) * 64 + lane]);
      acc2[c] = __builtin_amdgcn_mfma_f32_16x16x32_bf16(g[t], b, acc2[c], 0, 0, 0);
    }
  }
#pragma unroll
  for (int c = 0; c < 8; ++c) {
    float bc = bias[c * 16 + nn];
#pragma unroll
    for (int gg = 0; gg < 4; ++gg) {
      int row = r0 + q * 4 + gg;
      if (row < n) {
        float v = acc2[c][gg] + bc;
        if (ACT == 1) v = tanhf(v);
        else v = v / (1.f + __expf(-v));
        if (OUTF32) ((float*)outp)[(size_t)row * DD + c * 16 + nn] = v;
        else ((unsigned short*)outp)[(size_t)row * DD + c * 16 + nn] = f2bf(v);
      }
    }
  }
}

extern "C" void kernel_launch(void* const* d_in, const int* in_sizes, int n_in,
                              void* d_out, int out_size, void* d_ws, size_t ws_size,
                              hipStream_t stream) {
  const float* h_in = (const float*)d_in[0];
  const int* src    = (const int*)d_in[1];
  const int* dst    = (const int*)d_in[2];
  const float* W1   = (const float*)d_in[3];
  const float* b1   = (const float*)d_in[4];
  const float* W2   = (const float*)d_in[5];
  const float* b2   = (const float*)d_in[6];
  const float* Wself  = (const float*)d_in[7];
  const float* bself  = (const float*)d_in[8];
  const float* Wneigh = (const float*)d_in[9];
  const int N = in_sizes[0] / DD;
  const int E = in_sizes[1];
  float* out = (float*)d_out;

  char* ws = (char*)d_ws;
  size_t off = 0;
  auto alloc = [&](size_t bytes) -> char* {
    char* p = ws + off;
    off = (off + bytes + 255) & ~(size_t)255;
    return p;
  };
  unsigned* wfrag = (unsigned*)alloc(8 * 32768);
  unsigned* actA  = (unsigned*)alloc((size_t)N * 64 * 4);
  unsigned* actB  = (unsigned*)alloc((size_t)N * 64 * 4);
  int* esrc     = (int*)alloc((size_t)E * 4);
  int* degi     = (int*)alloc((size_t)N * 4);
  int* rowstart = (int*)alloc((size_t)(N + 1) * 4);
  int* cursor   = (int*)alloc((size_t)N * 4);
  int* incl     = (int*)alloc((size_t)N * 4);
  int* bsum     = (int*)alloc(65 * 4);

  hipMemsetAsync(degi, 0, (size_t)N * 4, stream);
  const int eb = (E + 255) / 256;
  const int nb = (N + 1023) / 1024;
  const int rstep = (N + 7) / 8;
  k_deg_prep<<<eb + 256, 256, 0, stream>>>(dst, degi, E, eb, W1, W2, Wself, Wneigh, wfrag);
  k_scan1<<<nb, 1024, 0, stream>>>(degi, incl, bsum, N);
  k_scan3<<<nb, 1024, 0, stream>>>(degi, incl, bsum, rowstart, cursor, N, nb);
  k_fill_r<<<eb * 8, 256, 0, stream>>>(src, dst, cursor, esrc, E, rstep);

  const int gb = (N + 63) / 64;
  const uint4* wf = (const uint4*)wfrag;

  k_fc12<<<gb, 256, 0, stream>>>(h_in, wf + 0 * 2048, wf + 1 * 2048, b1, b2,
                                 (unsigned short*)actB, N);

  const unsigned* cur = actB;
  unsigned* nxt = actA;
  for (int l = 0; l < 3; ++l) {
    const uint4* wsF = wf + (size_t)(2 + l) * 2048;
    const uint4* wnF = wf + (size_t)(5 + l) * 2048;
    const float* bs = bself + (size_t)l * DD;
    if (l < 2) {
      k_layer<2, false><<<gb, 256, 0, stream>>>((const uint4*)cur, rowstart, esrc, wsF, wnF, bs, nxt, N);
      const unsigned* tmp = cur;
      cur = nxt;
      nxt = (unsigned*)tmp;
    } else {
      k_layer<1, true><<<gb, 256, 0, stream>>>((const uint4*)cur, rowstart, esrc, wsF, wnF, bs, out, N);
    }
  }
}

// Round 8
// 333.522 us; speedup vs baseline: 1.2624x; 1.2624x over previous
//
#include <hip/hip_runtime.h>
#include <stdint.h>

#define DD 128
#define LDSROW 136  // 128 cols + 8 pad (ushort) -> 272B row stride

typedef __attribute__((ext_vector_type(8))) short short8;
typedef __attribute__((ext_vector_type(4))) float float4v;

// ---------- bf16 helpers (RTNE) ----------
__device__ __forceinline__ unsigned short f2bf(float f) {
  unsigned u = __float_as_uint(f);
  unsigned r = u + 0x7fffu + ((u >> 16) & 1u);
  return (unsigned short)(r >> 16);
}
__device__ __forceinline__ unsigned pack2(float a, float b) {
  return (unsigned)f2bf(a) | ((unsigned)f2bf(b) << 16);
}
__device__ __forceinline__ float2 unpack2(unsigned p) {
  float2 r;
  r.x = __uint_as_float(p << 16);
  r.y = __uint_as_float(p & 0xffff0000u);
  return r;
}

// ---------- CSR build: deg atomics + weight prep fused ----------
__global__ __launch_bounds__(256) void k_deg_prep(const int* __restrict__ dst, int* deg, int e, int eb,
                                                  const float* __restrict__ W1, const float* __restrict__ W2,
                                                  const float* __restrict__ Wself, const float* __restrict__ Wneigh,
                                                  unsigned* __restrict__ wfrag) {
  int b = blockIdx.x;
  if (b < eb) {
    int i = b * 256 + threadIdx.x;
    if (i < e) atomicAdd(&deg[dst[i]], 1);
  } else {
    int gid = (b - eb) * 256 + threadIdx.x;  // 0 .. 65535
    int m = gid >> 13;
    int r = gid & 8191;
    int p = r & 3;
    int lane = (r >> 2) & 63;
    int t = (r >> 8) & 3;
    int c = r >> 10;
    const float* W;
    if (m == 0) W = W1;
    else if (m == 1) W = W2;
    else if (m < 5) W = Wself + (size_t)(m - 2) * DD * DD;
    else W = Wneigh + (size_t)(m - 5) * DD * DD;
    int n = c * 16 + (lane & 15);
    int k = t * 32 + (lane >> 4) * 8 + 2 * p;
    wfrag[gid] = pack2(W[(size_t)k * DD + n], W[(size_t)(k + 1) * DD + n]);
  }
}

__global__ __launch_bounds__(1024) void k_scan1(const int* __restrict__ deg, int* __restrict__ incl,
                                                int* __restrict__ bsum, int n) {
  __shared__ int sh[1024];
  int t = threadIdx.x;
  int i = blockIdx.x * 1024 + t;
  int v = (i < n) ? deg[i] : 0;
  sh[t] = v;
  __syncthreads();
#pragma unroll
  for (int off = 1; off < 1024; off <<= 1) {
    int add = (t >= off) ? sh[t - off] : 0;
    __syncthreads();
    sh[t] += add;
    __syncthreads();
  }
  if (i < n) incl[i] = sh[t];
  if (t == 1023) bsum[blockIdx.x] = sh[1023];
}

__global__ __launch_bounds__(1024) void k_scan3(const int* __restrict__ deg, const int* __restrict__ incl,
                                                const int* __restrict__ bsum, int* __restrict__ rowstart,
                                                int* __restrict__ cursor, int n, int nb) {
  __shared__ int sboff;
  int t = threadIdx.x;
  if (t < 64) {
    int orig = (t < nb) ? bsum[t] : 0;
    int v = orig;
#pragma unroll
    for (int off = 1; off < 64; off <<= 1) {
      int u = __shfl_up(v, off);
      if (t >= off) v += u;
    }
    if (t == (int)blockIdx.x) sboff = v - orig;
  }
  __syncthreads();
  int i = blockIdx.x * 1024 + t;
  if (i >= n) return;
  int d = deg[i];
  int excl = sboff + incl[i] - d;
  rowstart[i] = excl;
  cursor[i] = excl;
  if (i == n - 1) rowstart[n] = excl + d;
}

// ---------- range-partitioned fill (L2-local write windows) ----------
__global__ __launch_bounds__(256) void k_fill_r(const int* __restrict__ src, const int* __restrict__ dst,
                                                int* cursor, int* __restrict__ esrc, int e, int rstep) {
  int range = blockIdx.x & 7;
  int i = (blockIdx.x >> 3) * 256 + threadIdx.x;
  if (i >= e) return;
  int d = dst[i];
  int lo = range * rstep;
  if (d >= lo && d < lo + rstep) {
    int p = atomicAdd(&cursor[d], 1);
    esrc[p] = src[i];
  }
}

// ---------- mean aggregation: 1 row/wave, 4 groups x 16 lanes, 16 edges (4 uint4/lane) in flight ----------
__global__ __launch_bounds__(256) void k_aggr(const uint4* __restrict__ h, const int* __restrict__ rowstart,
                                              const int* __restrict__ esrc, uint4* __restrict__ out, int n) {
  int wave = threadIdx.x >> 6, lane = threadIdx.x & 63;
  int g = lane >> 4, nn = lane & 15;
  int r = blockIdx.x * 4 + wave;
  if (r >= n) return;
  int ru = __builtin_amdgcn_readfirstlane(r);
  int beg = rowstart[ru], end = rowstart[ru + 1];
  int cnt = end - beg;
  float acc[8];
#pragma unroll
  for (int i = 0; i < 8; ++i) acc[i] = 0.f;
  int base = 0;
  for (; base + 16 <= cnt; base += 16) {  // 4 gathers in flight per lane
    int j0 = beg + base + g;
    int s0 = esrc[j0];
    int s1 = esrc[j0 + 4];
    int s2 = esrc[j0 + 8];
    int s3 = esrc[j0 + 12];
    uint4 v0 = h[(size_t)s0 * 16 + nn];
    uint4 v1 = h[(size_t)s1 * 16 + nn];
    uint4 v2 = h[(size_t)s2 * 16 + nn];
    uint4 v3 = h[(size_t)s3 * 16 + nn];
    const unsigned* u0 = (const unsigned*)&v0;
    const unsigned* u1 = (const unsigned*)&v1;
    const unsigned* u2 = (const unsigned*)&v2;
    const unsigned* u3 = (const unsigned*)&v3;
#pragma unroll
    for (int k = 0; k < 4; ++k) {
      float2 f0 = unpack2(u0[k]), f1 = unpack2(u1[k]);
      float2 f2 = unpack2(u2[k]), f3 = unpack2(u3[k]);
      acc[2 * k]     += (f0.x + f1.x) + (f2.x + f3.x);
      acc[2 * k + 1] += (f0.y + f1.y) + (f2.y + f3.y);
    }
  }
  for (; base + 8 <= cnt; base += 8) {
    int j0 = beg + base + g;
    int s0 = esrc[j0];
    int s1 = esrc[j0 + 4];
    uint4 v0 = h[(size_t)s0 * 16 + nn];
    uint4 v1 = h[(size_t)s1 * 16 + nn];
    const unsigned* u0 = (const unsigned*)&v0;
    const unsigned* u1 = (const unsigned*)&v1;
#pragma unroll
    for (int k = 0; k < 4; ++k) {
      float2 f0 = unpack2(u0[k]), f1 = unpack2(u1[k]);
      acc[2 * k] += f0.x + f1.x;
      acc[2 * k + 1] += f0.y + f1.y;
    }
  }
  if (base + g < cnt) {
    int s = esrc[beg + base + g];
    uint4 v = h[(size_t)s * 16 + nn];
    const unsigned* u = (const unsigned*)&v;
#pragma unroll
    for (int k = 0; k < 4; ++k) {
      float2 f = unpack2(u[k]);
      acc[2 * k] += f.x;
      acc[2 * k + 1] += f.y;
    }
  }
  if (base + 4 + g < cnt) {
    int s = esrc[beg + base + 4 + g];
    uint4 v = h[(size_t)s * 16 + nn];
    const unsigned* u = (const unsigned*)&v;
#pragma unroll
    for (int k = 0; k < 4; ++k) {
      float2 f = unpack2(u[k]);
      acc[2 * k] += f.x;
      acc[2 * k + 1] += f.y;
    }
  }
#pragma unroll
  for (int k = 0; k < 8; ++k) {
    acc[k] += __shfl_xor(acc[k], 16, 64);
    acc[k] += __shfl_xor(acc[k], 32, 64);
  }
  if (g == 0) {
    float inv = 1.0f / (float)(cnt > 1 ? cnt : 1);
    uint4 o;
    o.x = pack2(acc[0] * inv, acc[1] * inv);
    o.y = pack2(acc[2] * inv, acc[3] * inv);
    o.z = pack2(acc[4] * inv, acc[5] * inv);
    o.w = pack2(acc[6] * inv, acc[7] * inv);
    out[(size_t)r * 16 + nn] = o;
  }
}

// ---------- fused fc_in: out = tanh(h@W1+b1)@W2+b2  (bf16 out), 64 rows/block ----------
__global__ __launch_bounds__(256) void k_fc12(const float* __restrict__ h,
                                              const uint4* __restrict__ wf1, const uint4* __restrict__ wf2,
                                              const float* __restrict__ b1, const float* __restrict__ b2,
                                              unsigned short* __restrict__ outbf, int n) {
  __shared__ unsigned short sT[64 * LDSROW];
  int tid = threadIdx.x, w = tid >> 6, lane = tid & 63;
  int q = lane >> 4, nn = lane & 15;
  int r0 = (blockIdx.x * 4 + w) * 16;
  int rr = r0 + nn; if (rr >= n) rr = n - 1;
  short8 a[4];
  {
    const float* X = h + (size_t)rr * DD;
#pragma unroll
    for (int t = 0; t < 4; ++t) {
      int k0 = t * 32 + q * 8;
      float4 f0 = *(const float4*)&X[k0];
      float4 f1 = *(const float4*)&X[k0 + 4];
      uint4 u;
      u.x = pack2(f0.x, f0.y); u.y = pack2(f0.z, f0.w);
      u.z = pack2(f1.x, f1.y); u.w = pack2(f1.z, f1.w);
      a[t] = __builtin_bit_cast(short8, u);
    }
  }
  float4v acc[8];
#pragma unroll
  for (int c = 0; c < 8; ++c) acc[c] = (float4v){0.f, 0.f, 0.f, 0.f};
#pragma unroll
  for (int c = 0; c < 8; ++c) {
#pragma unroll
    for (int t = 0; t < 4; ++t) {
      short8 b = __builtin_bit_cast(short8, wf1[(c * 4 + t) * 64 + lane]);
      acc[c] = __builtin_amdgcn_mfma_f32_16x16x32_bf16(a[t], b, acc[c], 0, 0, 0);
    }
  }
#pragma unroll
  for (int c = 0; c < 8; ++c) {
    float bc = b1[c * 16 + nn];
#pragma unroll
    for (int g = 0; g < 4; ++g) {
      int lr = w * 16 + q * 4 + g;
      sT[lr * LDSROW + c * 16 + nn] = f2bf(tanhf(acc[c][g] + bc));
    }
  }
  __syncthreads();
  short8 a2[4];
#pragma unroll
  for (int t = 0; t < 4; ++t) {
    const uint4* p = (const uint4*)&sT[(w * 16 + nn) * LDSROW + (t * 4 + q) * 8];
    a2[t] = __builtin_bit_cast(short8, *p);
  }
  float4v acc2[8];
#pragma unroll
  for (int c = 0; c < 8; ++c) acc2[c] = (float4v){0.f, 0.f, 0.f, 0.f};
#pragma unroll
  for (int c = 0; c < 8; ++c) {
#pragma unroll
    for (int t = 0; t < 4; ++t) {
      short8 b = __builtin_bit_cast(short8, wf2[(c * 4 + t) * 64 + lane]);
      acc2[c] = __builtin_amdgcn_mfma_f32_16x16x32_bf16(a2[t], b, acc2[c], 0, 0, 0);
    }
  }
#pragma unroll
  for (int c = 0; c < 8; ++c) {
    float bc = b2[c * 16 + nn];
#pragma unroll
    for (int g = 0; g < 4; ++g) {
      int row = r0 + q * 4 + g;
      if (row < n) outbf[(size_t)row * DD + c * 16 + nn] = f2bf(acc2[c][g] + bc);
    }
  }
}

// ---------- lean SAGE GEMM: out = act(X@Ws + b + G@Wn). No LDS, no barrier. ----------
// ACT: 1 tanh, 2 silu
template <int ACT, bool OUTF32>
__global__ __launch_bounds__(256) void k_sage(const uint4* __restrict__ X, const uint4* __restrict__ G,
                                              const uint4* __restrict__ wfs, const uint4* __restrict__ wfn,
                                              const float* __restrict__ bias, void* __restrict__ outp, int n) {
  int tid = threadIdx.x, w = tid >> 6, lane = tid & 63;
  int q = lane >> 4, nn = lane & 15;
  int r0 = (blockIdx.x * 4 + w) * 16;
  int rr = r0 + nn; if (rr >= n) rr = n - 1;
  short8 a[4], g[4];
  {
    const uint4* Xr = X + (size_t)rr * 16;
    const uint4* Gr = G + (size_t)rr * 16;
#pragma unroll
    for (int t = 0; t < 4; ++t) {
      a[t] = __builtin_bit_cast(short8, Xr[t * 4 + q]);
      g[t] = __builtin_bit_cast(short8, Gr[t * 4 + q]);
    }
  }
  float4v acc[8];
#pragma unroll
  for (int c = 0; c < 8; ++c) acc[c] = (float4v){0.f, 0.f, 0.f, 0.f};
#pragma unroll
  for (int c = 0; c < 8; ++c) {
#pragma unroll
    for (int t = 0; t < 4; ++t) {
      short8 b = __builtin_bit_cast(short8, wfs[(c * 4 + t) * 64 + lane]);
      acc[c] = __builtin_amdgcn_mfma_f32_16x16x32_bf16(a[t], b, acc[c], 0, 0, 0);
    }
#pragma unroll
    for (int t = 0; t < 4; ++t) {
      short8 b = __builtin_bit_cast(short8, wfn[(c * 4 + t) * 64 + lane]);
      acc[c] = __builtin_amdgcn_mfma_f32_16x16x32_bf16(g[t], b, acc[c], 0, 0, 0);
    }
  }
#pragma unroll
  for (int c = 0; c < 8; ++c) {
    float bc = bias[c * 16 + nn];
#pragma unroll
    for (int gg = 0; gg < 4; ++gg) {
      int row = r0 + q * 4 + gg;
      if (row < n) {
        float v = acc[c][gg] + bc;
        if (ACT == 1) v = tanhf(v);
        else v = v / (1.f + __expf(-v));
        if (OUTF32) ((float*)outp)[(size_t)row * DD + c * 16 + nn] = v;
        else ((unsigned short*)outp)[(size_t)row * DD + c * 16 + nn] = f2bf(v);
      }
    }
  }
}

extern "C" void kernel_launch(void* const* d_in, const int* in_sizes, int n_in,
                              void* d_out, int out_size, void* d_ws, size_t ws_size,
                              hipStream_t stream) {
  const float* h_in = (const float*)d_in[0];
  const int* src    = (const int*)d_in[1];
  const int* dst    = (const int*)d_in[2];
  const float* W1   = (const float*)d_in[3];
  const float* b1   = (const float*)d_in[4];
  const float* W2   = (const float*)d_in[5];
  const float* b2   = (const float*)d_in[6];
  const float* Wself  = (const float*)d_in[7];
  const float* bself  = (const float*)d_in[8];
  const float* Wneigh = (const float*)d_in[9];
  const int N = in_sizes[0] / DD;
  const int E = in_sizes[1];
  float* out = (float*)d_out;

  char* ws = (char*)d_ws;
  size_t off = 0;
  auto alloc = [&](size_t bytes) -> char* {
    char* p = ws + off;
    off = (off + bytes + 255) & ~(size_t)255;
    return p;
  };
  unsigned* wfrag = (unsigned*)alloc(8 * 32768);
  unsigned* actA  = (unsigned*)alloc((size_t)N * 64 * 4);
  unsigned* actB  = (unsigned*)alloc((size_t)N * 64 * 4);
  unsigned* neigh = (unsigned*)alloc((size_t)N * 64 * 4);
  int* esrc     = (int*)alloc((size_t)E * 4);
  int* degi     = (int*)alloc((size_t)N * 4);
  int* rowstart = (int*)alloc((size_t)(N + 1) * 4);
  int* cursor   = (int*)alloc((size_t)N * 4);
  int* incl     = (int*)alloc((size_t)N * 4);
  int* bsum     = (int*)alloc(65 * 4);

  hipMemsetAsync(degi, 0, (size_t)N * 4, stream);
  const int eb = (E + 255) / 256;
  const int nb = (N + 1023) / 1024;
  const int rstep = (N + 7) / 8;
  k_deg_prep<<<eb + 256, 256, 0, stream>>>(dst, degi, E, eb, W1, W2, Wself, Wneigh, wfrag);
  k_scan1<<<nb, 1024, 0, stream>>>(degi, incl, bsum, N);
  k_scan3<<<nb, 1024, 0, stream>>>(degi, incl, bsum, rowstart, cursor, N, nb);
  k_fill_r<<<eb * 8, 256, 0, stream>>>(src, dst, cursor, esrc, E, rstep);

  const int gb = (N + 63) / 64;
  const int ab = (N + 3) / 4;
  const uint4* wf = (const uint4*)wfrag;

  k_fc12<<<gb, 256, 0, stream>>>(h_in, wf + 0 * 2048, wf + 1 * 2048, b1, b2,
                                 (unsigned short*)actB, N);

  const unsigned* cur = actB;
  unsigned* nxt = actA;
  for (int l = 0; l < 3; ++l) {
    k_aggr<<<ab, 256, 0, stream>>>((const uint4*)cur, rowstart, esrc, (uint4*)neigh, N);
    const uint4* wsF = wf + (size_t)(2 + l) * 2048;
    const uint4* wnF = wf + (size_t)(5 + l) * 2048;
    const float* bs = bself + (size_t)l * DD;
    if (l < 2) {
      k_sage<2, false><<<gb, 256, 0, stream>>>((const uint4*)cur, (const uint4*)neigh, wsF, wnF, bs, nxt, N);
      const unsigned* tmp = cur;
      cur = nxt;
      nxt = (unsigned*)tmp;
    } else {
      k_sage<1, true><<<gb, 256, 0, stream>>>((const uint4*)cur, (const uint4*)neigh, wsF, wnF, bs, out, N);
    }
  }
}